// Round 3
// baseline (124.657 us; speedup 1.0000x reference)
//
#include <hip/hip_runtime.h>
#include <hip/hip_bf16.h>

// Problem: B=32, S=512, P=512, D=768
//   M = B*S = 16384 tokens, N = P = 512 prototypes, K = D = 768
// out[0 .. M*N)            = distances  ||x_m - p_n||^2  (fp32)
// out[M*N .. M*N + N*K)    = prototypes (fp32 passthrough)
//
// R8 = R7 + (a) MFMA operand swap, (b) depth-2 proto prefetch.
//   R5 and R7 (totally different schedules) both measured ~45 us with every
//   pipe idle -> shared-invariant latency bottleneck: depth-1 fragment
//   prefetch (~300cyc L2 latency vs ~40cyc MFMA cover) and scalar dword
//   epilogue stores (1 instr / output element, 4 scattered segments each).
//   (a) swap: pass proto-frag as A-operand, token-frag as B-operand. Per-lane
//       A/B layouts are identical (lane&15 = Arow/Bcol, quad = k-slice), so
//       this is argument reordering only; D becomes [proto, token] and the 4
//       acc regs = 4 CONSECUTIVE protos -> float4 stores (8/thread vs 32).
//   (b) A0/A1/A2 rotation: MFMAs consume fragments loaded 2 k-steps ahead.
//   Everything else (K-chunk dbuf staging, XCD swizzle, 512 blocks x 512 thr,
//   64 tok x 256 prot per block) unchanged from the verified R7.

#define M_TOK 16384
#define N_PROT 512
#define K_DIM 768
#define BKC 128              // K-chunk staged in LDS
#define NKC (K_DIM / BKC)    // 6
#define NSK (K_DIM / 32)     // 24 MFMA k-steps
#define ASTR 136             // LDS row stride (bf16 units): 128 + 8 pad

typedef __attribute__((ext_vector_type(4))) float f32x4;
typedef __attribute__((ext_vector_type(8))) short bf16x8;

__device__ inline unsigned short f2bf(float f) {
    unsigned int u = __float_as_uint(f);
    u += 0x7fffu + ((u >> 16) & 1u);
    return (unsigned short)(u >> 16);
}

// One wave per prototype row: bf16 convert + ||p||^2 + fp32 passthrough copy.
__global__ __launch_bounds__(256) void prep_b(
    const float* __restrict__ p,
    unsigned short* __restrict__ b_bf, float* __restrict__ p_sq,
    float* __restrict__ proto_out)
{
    const int row  = blockIdx.x * 4 + (threadIdx.x >> 6);
    const int lane = threadIdx.x & 63;

    const float4* src4 = (const float4*)(p + (size_t)row * K_DIM);
    unsigned short* dst = b_bf + (size_t)row * K_DIM;
    float4* pout4 = (float4*)(proto_out + (size_t)row * K_DIM);

    float ssum = 0.0f;
#pragma unroll
    for (int j = 0; j < 3; ++j) {
        const int idx = lane + j * 64;
        float4 v = src4[idx];
        ssum += v.x * v.x + v.y * v.y + v.z * v.z + v.w * v.w;
        ushort4 b;
        b.x = f2bf(v.x); b.y = f2bf(v.y); b.z = f2bf(v.z); b.w = f2bf(v.w);
        ((ushort4*)dst)[idx] = b;
        pout4[idx] = v;
    }
#pragma unroll
    for (int off = 32; off > 0; off >>= 1) ssum += __shfl_down(ssum, off);
    if (lane == 0) p_sq[row] = ssum;
}

__global__ __launch_bounds__(512, 4) void dist_main(
    const float* __restrict__ X,             // [M,K] fp32 tokens
    const unsigned short* __restrict__ Bb,   // [N,K] bf16 prototypes (ws)
    const float* __restrict__ p_sq,          // [N] fp32
    float* __restrict__ out)                 // [M,N] fp32 distances
{
    __shared__ unsigned short lds_a[2][64 * ASTR];   // 2 x 17408 B = 34816 B
    __shared__ float lds_xsq[64];

    // ---- block mapping: XCD-chunked swizzle, pair-adjacent N-halves ----
    const int bid     = blockIdx.x;                    // 0..511
    const int logical = (bid & 7) * 64 + (bid >> 3);   // bijective over 0..511
    const int ms = logical >> 1;                       // M-stripe 0..255
    const int nh = logical & 1;                        // N half
    const int bm = ms << 6;
    const int bn = nh << 8;

    const int tid  = threadIdx.x;
    const int wave = tid >> 6;           // 0..7
    const int lane = tid & 63;
    const int wn   = bn + (wave << 5);   // wave's 32-proto slice of N
    const int quad = lane >> 4;          // 0..3
    const int l16  = lane & 15;

    // ---- staging mapping: 512 thr stage a 64x128 fp32 chunk (4 float4/thr) ----
    const int ar = tid >> 3;             // row 0..63
    const int ac = tid & 7;              // float4 col base
    const float* aptr = X + (size_t)(bm + ar) * K_DIM + ac * 4;

    float asq = 0.0f;

    // prologue: stage chunk 0
    {
        float4 v0 = *(const float4*)(aptr);
        float4 v1 = *(const float4*)(aptr + 32);
        float4 v2 = *(const float4*)(aptr + 64);
        float4 v3 = *(const float4*)(aptr + 96);
        float4 vv[4] = {v0, v1, v2, v3};
#pragma unroll
        for (int j = 0; j < 4; ++j) {
            float4 v = vv[j];
            asq += v.x * v.x + v.y * v.y + v.z * v.z + v.w * v.w;
            ushort4 u;
            u.x = f2bf(v.x); u.y = f2bf(v.y); u.z = f2bf(v.z); u.w = f2bf(v.w);
            *(ushort4*)&lds_a[0][ar * ASTR + (ac + 8 * j) * 4] = u;
        }
    }
    __syncthreads();

    // ---- proto (A-operand) fragments: global->VGPR, depth-2 pipeline ----
    // lane holds proto row (wn + pt*16 + l16), k-slice quad*8 + [0,8)
    const unsigned short* pb = Bb + (size_t)(wn + l16) * K_DIM + quad * 8;

    bf16x8 A0[2], A1[2], A2[2];
    A0[0] = *(const bf16x8*)(pb);
    A0[1] = *(const bf16x8*)(pb + 16 * K_DIM);
    A1[0] = *(const bf16x8*)(pb + 32);
    A1[1] = *(const bf16x8*)(pb + 16 * K_DIM + 32);

    const f32x4 zero = {0.0f, 0.0f, 0.0f, 0.0f};
    f32x4 acc[2][4];                     // [proto group][token group]
#pragma unroll
    for (int pt = 0; pt < 2; ++pt)
#pragma unroll
        for (int tt = 0; tt < 4; ++tt) acc[pt][tt] = zero;

    for (int kc = 0; kc < NKC; ++kc) {
        // issue next A-chunk global loads early (hide under this chunk's MFMAs)
        float4 s0, s1, s2, s3;
        if (kc + 1 < NKC) {
            const float* ap = aptr + (kc + 1) * BKC;
            s0 = *(const float4*)(ap);
            s1 = *(const float4*)(ap + 32);
            s2 = *(const float4*)(ap + 64);
            s3 = *(const float4*)(ap + 96);
        }

#pragma unroll
        for (int s = 0; s < 4; ++s) {
            const int kk = kc * 4 + s;
            if (kk + 2 < NSK) {          // uniform scalar branch, depth-2
                const int kn = (kk + 2) * 32;
                A2[0] = *(const bf16x8*)(pb + kn);
                A2[1] = *(const bf16x8*)(pb + 16 * K_DIM + kn);
            }

            bf16x8 tf[4];                // token (B-operand) frags from LDS
#pragma unroll
            for (int tt = 0; tt < 4; ++tt)
                tf[tt] = *(const bf16x8*)&lds_a[kc & 1]
                    [(tt * 16 + l16) * ASTR + s * 32 + quad * 8];

#pragma unroll
            for (int tt = 0; tt < 4; ++tt) {
                acc[0][tt] = __builtin_amdgcn_mfma_f32_16x16x32_bf16(
                    A0[0], tf[tt], acc[0][tt], 0, 0, 0);
                acc[1][tt] = __builtin_amdgcn_mfma_f32_16x16x32_bf16(
                    A0[1], tf[tt], acc[1][tt], 0, 0, 0);
            }
            A0[0] = A1[0]; A0[1] = A1[1];
            A1[0] = A2[0]; A1[1] = A2[1];
        }

        // convert + write next chunk into the other buffer, then one barrier
        if (kc + 1 < NKC) {
            unsigned short* aw = &lds_a[(kc + 1) & 1][ar * ASTR + ac * 4];
            float4 vv[4] = {s0, s1, s2, s3};
#pragma unroll
            for (int j = 0; j < 4; ++j) {
                float4 v = vv[j];
                asq += v.x * v.x + v.y * v.y + v.z * v.z + v.w * v.w;
                ushort4 u;
                u.x = f2bf(v.x); u.y = f2bf(v.y); u.z = f2bf(v.z); u.w = f2bf(v.w);
                *(ushort4*)(aw + 8 * j * 4) = u;
            }
        }
        __syncthreads();
    }

    // ---- x_sq: reduce over the 8 staging threads of each row ----
#pragma unroll
    for (int off = 1; off < 8; off <<= 1) asq += __shfl_xor(asq, off);
    if (ac == 0) lds_xsq[ar] = asq;
    __syncthreads();

    // ---- epilogue (swapped layout): D row = proto = quad*4+i, col = token = l16
    //      -> 4 acc regs are 4 consecutive protos -> float4 stores ----
    float4 ps4[2];
    ps4[0] = *(const float4*)&p_sq[wn + quad * 4];
    ps4[1] = *(const float4*)&p_sq[wn + 16 + quad * 4];

#pragma unroll
    for (int tt = 0; tt < 4; ++tt) {
        const float xs = lds_xsq[tt * 16 + l16];
        float* orow = out + (size_t)(bm + tt * 16 + l16) * N_PROT + wn + quad * 4;
        float4 o0, o1;
        o0.x = xs + ps4[0].x - 2.0f * acc[0][tt][0];
        o0.y = xs + ps4[0].y - 2.0f * acc[0][tt][1];
        o0.z = xs + ps4[0].z - 2.0f * acc[0][tt][2];
        o0.w = xs + ps4[0].w - 2.0f * acc[0][tt][3];
        o1.x = xs + ps4[1].x - 2.0f * acc[1][tt][0];
        o1.y = xs + ps4[1].y - 2.0f * acc[1][tt][1];
        o1.z = xs + ps4[1].z - 2.0f * acc[1][tt][2];
        o1.w = xs + ps4[1].w - 2.0f * acc[1][tt][3];
        *(float4*)(orow)      = o0;
        *(float4*)(orow + 16) = o1;
    }
}

extern "C" void kernel_launch(void* const* d_in, const int* in_sizes, int n_in,
                              void* d_out, int out_size, void* d_ws, size_t ws_size,
                              hipStream_t stream) {
    const float* inputs = (const float*)d_in[0];   // [32,512,768] fp32
    const float* protos = (const float*)d_in[1];   // [512,768]    fp32
    float* out = (float*)d_out;
    float* proto_out = out + (size_t)M_TOK * N_PROT;   // second tuple element

    // ws layout: b_bf 512*768*2 = 786,432 B ; p_sq 512*4 = 2,048 B
    char* ws = (char*)d_ws;
    unsigned short* b_bf = (unsigned short*)ws;
    float* p_sq = (float*)(ws + 786432);

    prep_b<<<128, 256, 0, stream>>>(protos, b_bf, p_sq, proto_out);
    // 256 M-stripes x 2 N-halves = 512 blocks
    dist_main<<<2 * (M_TOK / 64), 512, 0, stream>>>(inputs, b_bf, p_sq, out);
}